// Round 16
// baseline (464.482 us; speedup 1.0000x reference)
//
#include <hip/hip_runtime.h>

typedef __attribute__((ext_vector_type(4))) float f32x4;
typedef __attribute__((ext_vector_type(16))) float f32x16;
typedef __attribute__((ext_vector_type(8))) short short8;
typedef __attribute__((ext_vector_type(4))) short short4v;

#define PADW(I) ((I) + ((I) >> 4))
#define WOFF(z) ((z) + ((z) >> 4))

constexpr int LROW = 4096;
constexpr int KW   = 64;
constexpr int HALO = 32;
constexpr int NLOG = LROW + 2 * HALO;         // 4160 entries = 130 blocks of 32
constexpr int XS_SIZE = PADW(NLOG - 1) + 1;   // 4419 f32 words (17676 B)

// Merged-level block layout (R15-verified): 32 entries/block, 3 levels:
//   byte(n, k) = 200*(n>>5) + 64*k + 2*(n&31)     (8B pad per 200B block)
constexpr int SLOT2 = 26000;       // 130 blocks * 200 B
constexpr int POOL2 = 2 * SLOT2;   // 52000 B -> 3 blocks/CU
static_assert(XS_SIZE * 4 <= SLOT2, "f32 y stage fits in buf1 region");

__device__ __forceinline__ float bfh2f(unsigned short h) {
  return __uint_as_float(((unsigned)h) << 16);
}
__device__ __forceinline__ unsigned short btrunc(float x) {
  return (unsigned short)(__float_as_uint(x) >> 16);
}
// exact scaled split: x = h + m*2^-8 + l*2^-16 + O(2^-24 x); all steps exact.
__device__ __forceinline__ void split3s(float x, unsigned short& h,
                                        unsigned short& m, unsigned short& l) {
  h = btrunc(x);
  float r1 = (x - bfh2f(h)) * 256.0f;
  m = btrunc(r1);
  float r2 = (r1 - bfh2f(m)) * 256.0f;
  l = btrunc(r2);
}
__device__ __forceinline__ float shrinkf(float c, float theta) {
  float a = fabsf(c) - theta;
  return (a > 0.0f) ? copysignf(a, c) : 0.0f;
}

// scalar conv (R6-proven): thread owns outputs [16t,16t+16), affine LDS base.
__device__ __forceinline__ void conv_row(const float* __restrict__ xw,
                                         const float* __restrict__ kn,
                                         float acc[16]) {
#pragma unroll
  for (int e = 0; e < 16; ++e) acc[e] = 0.0f;
#pragma unroll
  for (int m = 0; m < 79; ++m) {
    float wv = xw[WOFF(1 + m)];
    const int jlo = (m - 15 > 0) ? (m - 15) : 0;
    const int jhi = (m < 63) ? m : 63;
#pragma unroll
    for (int j = jlo; j <= jhi; ++j) acc[m - j] = fmaf(kn[j], wv, acc[m - j]);
  }
}

// Fused shrink -> exact split -> LDS store of 4 consecutive outputs
// (register-diet: 4-wide transient staging instead of 16-wide arrays).
__device__ __forceinline__ void store4(char* wp, const float c0, const float c1,
                                       const float c2, const float c3,
                                       float theta) {
  short4v h4, m4, l4;
  float cc[4] = {c0, c1, c2, c3};
#pragma unroll
  for (int i = 0; i < 4; ++i) {
    float xn = shrinkf(cc[i], theta);
    unsigned short h, m, lo; split3s(xn, h, m, lo);
    h4[i] = (short)h; m4[i] = (short)m; l4[i] = (short)lo;
  }
  *(short4v*)(wp)       = h4;
  *(short4v*)(wp + 64)  = m4;
  *(short4v*)(wp + 128) = l4;
}

// One block = one row. 4 waves; wave w owns x-indices [1024w, 1024w+1024) as
// ONE 32x32 D tile (R14-verified): col = lane&31, row e = (r&3)+8(r>>2)+4(l>>5).
// GEMM: D[e][p] = sum_q Kmat[e][q] * x[1024w+32p-32+q], q in [0,96), 6 kf of 16.
__global__ __launch_bounds__(256, 3) void ista_mfma(
    const float* __restrict__ y, const float* __restrict__ pulse,
    float* __restrict__ xout) {
  __shared__ __align__(16) char pool[POOL2];
  __shared__ float pl[KW];
  __shared__ float knl[KW];

  const int t = threadIdx.x, w = t >> 6, l = t & 63;
  const int lq = l & 31;              // D col / A row residue
  const int hi = l >> 5;              // k-subgroup
  const int row = blockIdx.x;

  if (t < KW) pl[t] = pulse[t];

  // zero buf0 halo blocks: block 0 (bytes [0,192)), block 129 ([25800,25992))
  if (t < 48) *(unsigned*)(pool + 4 * t) = 0u;
  if (t < 48) *(unsigned*)(pool + 25800 + 4 * t) = 0u;

  // stage y as f32 (PADW layout) into the buf1 region (for exact scalar bt)
  float* yw = (float*)(pool + SLOT2);
  if (t < HALO) { yw[PADW(t)] = 0.0f; yw[PADW(NLOG - HALO + t)] = 0.0f; }
  const float* yrow = y + (size_t)row * LROW;
#pragma unroll
  for (int q = 0; q < 4; ++q) {
    int i4 = q * 256 + t; float4 v = ((const float4*)yrow)[i4];
    yw[PADW(HALO + 4 * i4 + 0)] = v.x; yw[PADW(HALO + 4 * i4 + 1)] = v.y;
    yw[PADW(HALO + 4 * i4 + 2)] = v.z; yw[PADW(HALO + 4 * i4 + 3)] = v.w;
  }
  __syncthreads();                       // (A) pl, y staged

  float Lc = 0.0f;
#pragma unroll
  for (int j = 0; j < KW; ++j) Lc += pl[j] * pl[j];
  const float theta = 0.1f / Lc, invL = 1.0f / Lc;
  if (t < KW) knl[t] = pl[KW - 1 - t] * invL;

  // operator A-frags for I - K/L, exact scaled bf16x3 (R14-verified mapping)
  short8 Ah[6], Am[6], Al[6];
#pragma unroll
  for (int kf = 0; kf < 6; ++kf) {
#pragma unroll
    for (int j = 0; j < 8; ++j) {
      int q = 16 * kf + 8 * hi + j, d = q - lq - 1;
      float v = (d >= 0 && d < 64) ? pl[63 - d] * invL : 0.0f;
      float vc = ((q == lq + 32) ? 1.0f : 0.0f) - v;
      unsigned short h, m, lo; split3s(vc, h, m, lo);
      Ah[kf][j] = (short)h; Am[kf][j] = (short)m; Al[kf][j] = (short)lo;
    }
  }
  __syncthreads();                       // (B) knl visible

  // exact f32 B_term via scalar conv (one-time), thread-t element layout
  float bts[16];
  conv_row(yw + 17 * t, knl, bts);
  __syncthreads();                       // (C) all y reads done

  // re-layout bt through (dead) y region, read back in 32x32 C-layout
#pragma unroll
  for (int e = 0; e < 16; ++e) (yw + 17 * t)[WOFF(32 + e)] = bts[e];
  __syncthreads();                       // (D)

  f32x16 bt;
#pragma unroll
  for (int r = 0; r < 16; ++r) {
    const int e = (r & 3) + 8 * (r >> 2) + 4 * hi;
    bt[r] = yw[PADW(32 + 1024 * w + 32 * lq + e)];
  }
  __syncthreads();                       // (E) bt reads done; buf1 free

  // zero buf1 halo blocks
  if (t < 48) *(unsigned*)(pool + SLOT2 + 4 * t) = 0u;
  if (t < 48) *(unsigned*)(pool + SLOT2 + 25800 + 4 * t) = 0u;

  // lane-constant byte bases
  const int rbase = 200 * (32 * w + lq) + 16 * hi;    // B-frag b64 reads
  const int wbase = 200 * (32 * w + lq + 1) + 8 * hi; // C b64 writes
  constexpr float S8 = 1.0f / 256.0f, S16 = 1.0f / 65536.0f;

  // x1 = shrink(bt) -> buf1 (fused split+store per group)
  {
    char* wpb = pool + SLOT2 + wbase;
#pragma unroll
    for (int g = 0; g < 4; ++g)
      store4(wpb + 16 * g, bt[4 * g], bt[4 * g + 1], bt[4 * g + 2],
             bt[4 * g + 3], theta);
  }
  __syncthreads();                       // (F) x1 visible

  // 19 iterations; scale-grouped accumulators; double-buffer, 1 barrier/iter
  for (int it = 0; it < 19; ++it) {
    const int rs = (it & 1) ? 0 : SLOT2, ws = SLOT2 - rs;
    const char* rp = pool + rs + rbase;
    f32x16 ah = bt, am = (f32x16)0.0f, al = (f32x16)0.0f;
#pragma unroll
    for (int kf = 0; kf < 6; ++kf) {
      const char* p = rp + 200 * (kf >> 1) + 32 * (kf & 1);
      short4v h0 = *(const short4v*)(p);
      short4v h1 = *(const short4v*)(p + 8);
      short4v m0 = *(const short4v*)(p + 64);
      short4v m1 = *(const short4v*)(p + 72);
      short4v l0 = *(const short4v*)(p + 128);
      short4v l1 = *(const short4v*)(p + 136);
      short8 xh = __builtin_shufflevector(h0, h1, 0, 1, 2, 3, 4, 5, 6, 7);
      short8 xm = __builtin_shufflevector(m0, m1, 0, 1, 2, 3, 4, 5, 6, 7);
      short8 xl = __builtin_shufflevector(l0, l1, 0, 1, 2, 3, 4, 5, 6, 7);
      ah = __builtin_amdgcn_mfma_f32_32x32x16_bf16(Ah[kf], xh, ah, 0, 0, 0);
      am = __builtin_amdgcn_mfma_f32_32x32x16_bf16(Ah[kf], xm, am, 0, 0, 0);
      am = __builtin_amdgcn_mfma_f32_32x32x16_bf16(Am[kf], xh, am, 0, 0, 0);
      al = __builtin_amdgcn_mfma_f32_32x32x16_bf16(Ah[kf], xl, al, 0, 0, 0);
      al = __builtin_amdgcn_mfma_f32_32x32x16_bf16(Am[kf], xm, al, 0, 0, 0);
      al = __builtin_amdgcn_mfma_f32_32x32x16_bf16(Al[kf], xh, al, 0, 0, 0);
    }
    char* wpb = pool + ws + wbase;
#pragma unroll
    for (int g = 0; g < 4; ++g) {
      float c0 = fmaf(S16, al[4 * g + 0], fmaf(S8, am[4 * g + 0], ah[4 * g + 0]));
      float c1 = fmaf(S16, al[4 * g + 1], fmaf(S8, am[4 * g + 1], ah[4 * g + 1]));
      float c2 = fmaf(S16, al[4 * g + 2], fmaf(S8, am[4 * g + 2], ah[4 * g + 2]));
      float c3 = fmaf(S16, al[4 * g + 3], fmaf(S8, am[4 * g + 3], ah[4 * g + 3]));
      store4(wpb + 16 * g, c0, c1, c2, c3, theta);
    }
    __syncthreads();
  }

  // final x in buf0: thread t reads entries [16t+32,16t+48), reconstructs,
  // writes coalesced float4. base = byte(16t+32, 0).
  {
    const int base = 200 * ((t + 2) >> 1) + 32 * (t & 1);
    float o[16];
#pragma unroll
    for (int s = 0; s < 4; ++s) {
      const char* hp = pool + base + 8 * s;
      short4v hv = *(const short4v*)(hp);
      short4v mv = *(const short4v*)(hp + 64);
      short4v lv = *(const short4v*)(hp + 128);
#pragma unroll
      for (int c2 = 0; c2 < 4; ++c2) {
        float xv = fmaf(S8, bfh2f((unsigned short)mv[c2]),
                        bfh2f((unsigned short)hv[c2]));
        o[4 * s + c2] = fmaf(S16, bfh2f((unsigned short)lv[c2]), xv);
      }
    }
    float4* xr = (float4*)(xout + (size_t)row * LROW + 16 * t);
#pragma unroll
    for (int s = 0; s < 4; ++s)
      xr[s] = make_float4(o[4 * s], o[4 * s + 1], o[4 * s + 2], o[4 * s + 3]);
  }
}

// ---------------- MLP via bf16 MFMA (validated in R2) ----------------
__device__ __forceinline__ unsigned short f2bf(float f) {
  unsigned u = __float_as_uint(f);
  u += 0x7fffu + ((u >> 16) & 1u);      // RNE
  return (unsigned short)(u >> 16);
}

__global__ __launch_bounds__(256) void cast_w1(const float* __restrict__ W1,
                                               unsigned short* __restrict__ W1p) {
  const int kq = blockIdx.x;
  const int c  = threadIdx.x;
  short8 v;
#pragma unroll
  for (int j = 0; j < 8; ++j)
    v[j] = (short)f2bf(W1[(size_t)(kq * 8 + j) * 256 + c]);
  *(short8*)(W1p + ((size_t)kq * 256 + c) * 8) = v;
}

__global__ __launch_bounds__(256) void mlp_mfma(
    const float* __restrict__ x, const unsigned short* __restrict__ W1p,
    const float* __restrict__ b1, const float* __restrict__ W2,
    const float* __restrict__ b2, float* __restrict__ out1) {
  __shared__ short Ap[16 * 8 * 8];
  __shared__ short Bp[8 * 256 * 8];
  __shared__ float pr[4][16];

  const int t = threadIdx.x;
  const int w = t >> 6;
  const int l = t & 63;
  const int lrow = l & 15;
  const int lk   = l >> 4;
  const int row0 = blockIdx.x * 16;

  f32x4 acc[4];
#pragma unroll
  for (int n = 0; n < 4; ++n) acc[n] = (f32x4)0.0f;

  for (int kt = 0; kt < 64; ++kt) {
    __syncthreads();
    {
      const int r  = t >> 4;
      const int k4 = t & 15;
      const float4 v = *(const float4*)(x + (size_t)(row0 + r) * LROW + kt * 64 + k4 * 4);
      short4v a;
      a.x = (short)f2bf(v.x); a.y = (short)f2bf(v.y);
      a.z = (short)f2bf(v.z); a.w = (short)f2bf(v.w);
      const int kq = k4 >> 1, h = k4 & 1;
      *(short4v*)((char*)Ap + ((r * 8 + (kq ^ (r & 7))) * 16 + h * 8)) = a;
    }
    {
      const short8* src = (const short8*)(W1p + (size_t)kt * (8 * 256 * 8));
      short8* dst = (short8*)Bp;
#pragma unroll
      for (int i = 0; i < 8; ++i) dst[t + 256 * i] = src[t + 256 * i];
    }
    __syncthreads();
#pragma unroll
    for (int kf = 0; kf < 2; ++kf) {
      const int kq = kf * 4 + lk;
      short8 af = *(short8*)((char*)Ap + (lrow * 8 + (kq ^ (lrow & 7))) * 16);
#pragma unroll
      for (int n = 0; n < 4; ++n) {
        short8 bf = *(short8*)((char*)Bp + (kq * 256 + w * 64 + n * 16 + lrow) * 16);
        acc[n] = __builtin_amdgcn_mfma_f32_16x16x32_bf16(af, bf, acc[n], 0, 0, 0);
      }
    }
  }

  float s[4] = {0.0f, 0.0f, 0.0f, 0.0f};
#pragma unroll
  for (int n = 0; n < 4; ++n) {
    const int c = w * 64 + n * 16 + lrow;
    const float b1v = b1[c];
    const float w2v = W2[c];
#pragma unroll
    for (int i = 0; i < 4; ++i) {
      float f = acc[n][i] + b1v;
      f = fmaxf(f, 0.0f);
      s[i] = fmaf(f, w2v, s[i]);
    }
  }
#pragma unroll
  for (int off = 1; off < 16; off <<= 1) {
#pragma unroll
    for (int i = 0; i < 4; ++i) s[i] += __shfl_xor(s[i], off, 64);
  }
  if (lrow == 0) {
#pragma unroll
    for (int i = 0; i < 4; ++i) pr[w][lk * 4 + i] = s[i];
  }
  __syncthreads();
  if (t < 16) {
    out1[row0 + t] =
        (pr[0][t] + pr[1][t] + pr[2][t] + pr[3][t] + b2[0]) * (float)LROW;
  }
}

extern "C" void kernel_launch(void* const* d_in, const int* in_sizes, int n_in,
                              void* d_out, int out_size, void* d_ws, size_t ws_size,
                              hipStream_t stream) {
  const float* y     = (const float*)d_in[0];
  const float* pulse = (const float*)d_in[1];
  const float* W1    = (const float*)d_in[2];
  const float* b1    = (const float*)d_in[3];
  const float* W2    = (const float*)d_in[4];
  const float* b2    = (const float*)d_in[5];

  float* xout = (float*)d_out;
  float* out1 = xout + (size_t)LROW * LROW;
  unsigned short* W1p = (unsigned short*)d_ws;

  cast_w1<<<512, 256, 0, stream>>>(W1, W1p);
  ista_mfma<<<LROW, 256, 0, stream>>>(y, pulse, xout);
  mlp_mfma<<<LROW / 16, 256, 0, stream>>>(xout, W1p, b1, W2, b2, out1);
}

// Round 17
// 411.162 us; speedup vs baseline: 1.1297x; 1.1297x over previous
//
#include <hip/hip_runtime.h>

typedef __attribute__((ext_vector_type(4))) float f32x4;
typedef __attribute__((ext_vector_type(16))) float f32x16;
typedef __attribute__((ext_vector_type(8))) short short8;
typedef __attribute__((ext_vector_type(4))) short short4v;

#define PADW(I) ((I) + ((I) >> 4))
#define WOFF(z) ((z) + ((z) >> 4))

constexpr int LROW = 4096;
constexpr int KW   = 64;
constexpr int HALO = 32;
constexpr int NLOG = LROW + 2 * HALO;         // 4160 entries = 130 blocks of 32
constexpr int XS_SIZE = PADW(NLOG - 1) + 1;   // 4419 f32 words (17676 B)

// Merged-level block layout (R15/R16-verified): 32 entries/block, 3 levels:
//   byte(n, k) = 200*(n>>5) + 64*k + 2*(n&31)     (8B pad per 200B block)
constexpr int SLOT2 = 26000;       // 130 blocks * 200 B
constexpr int POOL2 = 2 * SLOT2;   // 52000 B
static_assert(XS_SIZE * 4 <= SLOT2, "f32 y stage fits in buf1 region");

__device__ __forceinline__ float bfh2f(unsigned short h) {
  return __uint_as_float(((unsigned)h) << 16);
}
__device__ __forceinline__ unsigned short btrunc(float x) {
  return (unsigned short)(__float_as_uint(x) >> 16);
}
// exact scaled split: x = h + m*2^-8 + l*2^-16 + O(2^-24 x); all steps exact.
__device__ __forceinline__ void split3s(float x, unsigned short& h,
                                        unsigned short& m, unsigned short& l) {
  h = btrunc(x);
  float r1 = (x - bfh2f(h)) * 256.0f;
  m = btrunc(r1);
  float r2 = (r1 - bfh2f(m)) * 256.0f;
  l = btrunc(r2);
}
__device__ __forceinline__ float shrinkf(float c, float theta) {
  float a = fabsf(c) - theta;
  return (a > 0.0f) ? copysignf(a, c) : 0.0f;
}

// scalar conv (R6-proven): thread owns outputs [16t,16t+16), affine LDS base.
__device__ __forceinline__ void conv_row(const float* __restrict__ xw,
                                         const float* __restrict__ kn,
                                         float acc[16]) {
#pragma unroll
  for (int e = 0; e < 16; ++e) acc[e] = 0.0f;
#pragma unroll
  for (int m = 0; m < 79; ++m) {
    float wv = xw[WOFF(1 + m)];
    const int jlo = (m - 15 > 0) ? (m - 15) : 0;
    const int jhi = (m < 63) ? m : 63;
#pragma unroll
    for (int j = jlo; j <= jhi; ++j) acc[m - j] = fmaf(kn[j], wv, acc[m - j]);
  }
}

// Fused shrink -> exact split -> LDS store of 4 consecutive outputs.
__device__ __forceinline__ void store4(char* wp, const float c0, const float c1,
                                       const float c2, const float c3,
                                       float theta) {
  short4v h4, m4, l4;
  float cc[4] = {c0, c1, c2, c3};
#pragma unroll
  for (int i = 0; i < 4; ++i) {
    float xn = shrinkf(cc[i], theta);
    unsigned short h, m, lo; split3s(xn, h, m, lo);
    h4[i] = (short)h; m4[i] = (short)m; l4[i] = (short)lo;
  }
  *(short4v*)(wp)       = h4;
  *(short4v*)(wp + 64)  = m4;
  *(short4v*)(wp + 128) = l4;
}

// One block = one row. 4 waves; wave w owns x-indices [1024w, 1024w+1024) as
// ONE 32x32 D tile (R14-verified): col = lane&31, row e = (r&3)+8(r>>2)+4(l>>5).
// GEMM: D[e][p] = sum_q Kmat[e][q] * x[1024w+32p-32+q], q in [0,96), 6 kf of 16.
// launch_bounds(256,2): 256-VGPR cap -> NO SPILL (R15/R16 lesson: the 32x32
// state needs ~200 regs; a 3-wave cap forces scratch round-trips).
__global__ __launch_bounds__(256, 2) void ista_mfma(
    const float* __restrict__ y, const float* __restrict__ pulse,
    float* __restrict__ xout) {
  __shared__ __align__(16) char pool[POOL2];
  __shared__ float pl[KW];
  __shared__ float knl[KW];

  const int t = threadIdx.x, w = t >> 6, l = t & 63;
  const int lq = l & 31;              // D col / A row residue
  const int hi = l >> 5;              // k-subgroup
  const int row = blockIdx.x;

  if (t < KW) pl[t] = pulse[t];

  // zero buf0 halo blocks: block 0 (bytes [0,192)), block 129 ([25800,25992))
  if (t < 48) *(unsigned*)(pool + 4 * t) = 0u;
  if (t < 48) *(unsigned*)(pool + 25800 + 4 * t) = 0u;

  // stage y as f32 (PADW layout) into the buf1 region (for exact scalar bt)
  float* yw = (float*)(pool + SLOT2);
  if (t < HALO) { yw[PADW(t)] = 0.0f; yw[PADW(NLOG - HALO + t)] = 0.0f; }
  const float* yrow = y + (size_t)row * LROW;
#pragma unroll
  for (int q = 0; q < 4; ++q) {
    int i4 = q * 256 + t; float4 v = ((const float4*)yrow)[i4];
    yw[PADW(HALO + 4 * i4 + 0)] = v.x; yw[PADW(HALO + 4 * i4 + 1)] = v.y;
    yw[PADW(HALO + 4 * i4 + 2)] = v.z; yw[PADW(HALO + 4 * i4 + 3)] = v.w;
  }
  __syncthreads();                       // (A) pl, y staged

  float Lc = 0.0f;
#pragma unroll
  for (int j = 0; j < KW; ++j) Lc += pl[j] * pl[j];
  const float theta = 0.1f / Lc, invL = 1.0f / Lc;
  if (t < KW) knl[t] = pl[KW - 1 - t] * invL;

  // operator A-frags for I - K/L, exact scaled bf16x3 (R14-verified mapping)
  short8 Ah[6], Am[6], Al[6];
#pragma unroll
  for (int kf = 0; kf < 6; ++kf) {
#pragma unroll
    for (int j = 0; j < 8; ++j) {
      int q = 16 * kf + 8 * hi + j, d = q - lq - 1;
      float v = (d >= 0 && d < 64) ? pl[63 - d] * invL : 0.0f;
      float vc = ((q == lq + 32) ? 1.0f : 0.0f) - v;
      unsigned short h, m, lo; split3s(vc, h, m, lo);
      Ah[kf][j] = (short)h; Am[kf][j] = (short)m; Al[kf][j] = (short)lo;
    }
  }
  __syncthreads();                       // (B) knl visible

  // exact f32 B_term via scalar conv (one-time), thread-t element layout
  float bts[16];
  conv_row(yw + 17 * t, knl, bts);
  __syncthreads();                       // (C) all y reads done

  // re-layout bt through (dead) y region, read back in 32x32 C-layout
#pragma unroll
  for (int e = 0; e < 16; ++e) (yw + 17 * t)[WOFF(32 + e)] = bts[e];
  __syncthreads();                       // (D)

  f32x16 bt;
#pragma unroll
  for (int r = 0; r < 16; ++r) {
    const int e = (r & 3) + 8 * (r >> 2) + 4 * hi;
    bt[r] = yw[PADW(32 + 1024 * w + 32 * lq + e)];
  }
  __syncthreads();                       // (E) bt reads done; buf1 free

  // zero buf1 halo blocks
  if (t < 48) *(unsigned*)(pool + SLOT2 + 4 * t) = 0u;
  if (t < 48) *(unsigned*)(pool + SLOT2 + 25800 + 4 * t) = 0u;

  // lane-constant byte bases
  const int rbase = 200 * (32 * w + lq) + 16 * hi;    // B-frag b64 reads
  const int wbase = 200 * (32 * w + lq + 1) + 8 * hi; // C b64 writes
  constexpr float S8 = 1.0f / 256.0f, S16 = 1.0f / 65536.0f;

  // x1 = shrink(bt) -> buf1
  {
    char* wpb = pool + SLOT2 + wbase;
#pragma unroll
    for (int g = 0; g < 4; ++g)
      store4(wpb + 16 * g, bt[4 * g], bt[4 * g + 1], bt[4 * g + 2],
             bt[4 * g + 3], theta);
  }
  __syncthreads();                       // (F) x1 visible

  // 19 iterations; scale-grouped accumulators; double-buffer, 1 barrier/iter.
  // Load phase fully hoisted ahead of the MFMA stream (ILP; no spill at 256).
  for (int it = 0; it < 19; ++it) {
    const int rs = (it & 1) ? 0 : SLOT2, ws = SLOT2 - rs;
    const char* rp = pool + rs + rbase;

    short8 xh[6], xm[6], xl[6];
#pragma unroll
    for (int kf = 0; kf < 6; ++kf) {
      const char* p = rp + 200 * (kf >> 1) + 32 * (kf & 1);
      short4v h0 = *(const short4v*)(p);
      short4v h1 = *(const short4v*)(p + 8);
      short4v m0 = *(const short4v*)(p + 64);
      short4v m1 = *(const short4v*)(p + 72);
      short4v l0 = *(const short4v*)(p + 128);
      short4v l1 = *(const short4v*)(p + 136);
      xh[kf] = __builtin_shufflevector(h0, h1, 0, 1, 2, 3, 4, 5, 6, 7);
      xm[kf] = __builtin_shufflevector(m0, m1, 0, 1, 2, 3, 4, 5, 6, 7);
      xl[kf] = __builtin_shufflevector(l0, l1, 0, 1, 2, 3, 4, 5, 6, 7);
    }

    f32x16 ah = bt, am = (f32x16)0.0f, al = (f32x16)0.0f;
#pragma unroll
    for (int kf = 0; kf < 6; ++kf) {
      ah = __builtin_amdgcn_mfma_f32_32x32x16_bf16(Ah[kf], xh[kf], ah, 0, 0, 0);
      am = __builtin_amdgcn_mfma_f32_32x32x16_bf16(Ah[kf], xm[kf], am, 0, 0, 0);
      am = __builtin_amdgcn_mfma_f32_32x32x16_bf16(Am[kf], xh[kf], am, 0, 0, 0);
      al = __builtin_amdgcn_mfma_f32_32x32x16_bf16(Ah[kf], xl[kf], al, 0, 0, 0);
      al = __builtin_amdgcn_mfma_f32_32x32x16_bf16(Am[kf], xm[kf], al, 0, 0, 0);
      al = __builtin_amdgcn_mfma_f32_32x32x16_bf16(Al[kf], xh[kf], al, 0, 0, 0);
    }

    char* wpb = pool + ws + wbase;
#pragma unroll
    for (int g = 0; g < 4; ++g) {
      float c0 = fmaf(S16, al[4 * g + 0], fmaf(S8, am[4 * g + 0], ah[4 * g + 0]));
      float c1 = fmaf(S16, al[4 * g + 1], fmaf(S8, am[4 * g + 1], ah[4 * g + 1]));
      float c2 = fmaf(S16, al[4 * g + 2], fmaf(S8, am[4 * g + 2], ah[4 * g + 2]));
      float c3 = fmaf(S16, al[4 * g + 3], fmaf(S8, am[4 * g + 3], ah[4 * g + 3]));
      store4(wpb + 16 * g, c0, c1, c2, c3, theta);
    }
    __syncthreads();
  }

  // final x in buf0: thread t reads entries [16t+32,16t+48), reconstructs,
  // writes coalesced float4. base = byte(16t+32, 0).
  {
    const int base = 200 * ((t + 2) >> 1) + 32 * (t & 1);
    float o[16];
#pragma unroll
    for (int s = 0; s < 4; ++s) {
      const char* hp = pool + base + 8 * s;
      short4v hv = *(const short4v*)(hp);
      short4v mv = *(const short4v*)(hp + 64);
      short4v lv = *(const short4v*)(hp + 128);
#pragma unroll
      for (int c2 = 0; c2 < 4; ++c2) {
        float xv = fmaf(S8, bfh2f((unsigned short)mv[c2]),
                        bfh2f((unsigned short)hv[c2]));
        o[4 * s + c2] = fmaf(S16, bfh2f((unsigned short)lv[c2]), xv);
      }
    }
    float4* xr = (float4*)(xout + (size_t)row * LROW + 16 * t);
#pragma unroll
    for (int s = 0; s < 4; ++s)
      xr[s] = make_float4(o[4 * s], o[4 * s + 1], o[4 * s + 2], o[4 * s + 3]);
  }
}

// ---------------- MLP via bf16 MFMA (validated in R2) ----------------
__device__ __forceinline__ unsigned short f2bf(float f) {
  unsigned u = __float_as_uint(f);
  u += 0x7fffu + ((u >> 16) & 1u);      // RNE
  return (unsigned short)(u >> 16);
}

__global__ __launch_bounds__(256) void cast_w1(const float* __restrict__ W1,
                                               unsigned short* __restrict__ W1p) {
  const int kq = blockIdx.x;
  const int c  = threadIdx.x;
  short8 v;
#pragma unroll
  for (int j = 0; j < 8; ++j)
    v[j] = (short)f2bf(W1[(size_t)(kq * 8 + j) * 256 + c]);
  *(short8*)(W1p + ((size_t)kq * 256 + c) * 8) = v;
}

__global__ __launch_bounds__(256) void mlp_mfma(
    const float* __restrict__ x, const unsigned short* __restrict__ W1p,
    const float* __restrict__ b1, const float* __restrict__ W2,
    const float* __restrict__ b2, float* __restrict__ out1) {
  __shared__ short Ap[16 * 8 * 8];
  __shared__ short Bp[8 * 256 * 8];
  __shared__ float pr[4][16];

  const int t = threadIdx.x;
  const int w = t >> 6;
  const int l = t & 63;
  const int lrow = l & 15;
  const int lk   = l >> 4;
  const int row0 = blockIdx.x * 16;

  f32x4 acc[4];
#pragma unroll
  for (int n = 0; n < 4; ++n) acc[n] = (f32x4)0.0f;

  for (int kt = 0; kt < 64; ++kt) {
    __syncthreads();
    {
      const int r  = t >> 4;
      const int k4 = t & 15;
      const float4 v = *(const float4*)(x + (size_t)(row0 + r) * LROW + kt * 64 + k4 * 4);
      short4v a;
      a.x = (short)f2bf(v.x); a.y = (short)f2bf(v.y);
      a.z = (short)f2bf(v.z); a.w = (short)f2bf(v.w);
      const int kq = k4 >> 1, h = k4 & 1;
      *(short4v*)((char*)Ap + ((r * 8 + (kq ^ (r & 7))) * 16 + h * 8)) = a;
    }
    {
      const short8* src = (const short8*)(W1p + (size_t)kt * (8 * 256 * 8));
      short8* dst = (short8*)Bp;
#pragma unroll
      for (int i = 0; i < 8; ++i) dst[t + 256 * i] = src[t + 256 * i];
    }
    __syncthreads();
#pragma unroll
    for (int kf = 0; kf < 2; ++kf) {
      const int kq = kf * 4 + lk;
      short8 af = *(short8*)((char*)Ap + (lrow * 8 + (kq ^ (lrow & 7))) * 16);
#pragma unroll
      for (int n = 0; n < 4; ++n) {
        short8 bf = *(short8*)((char*)Bp + (kq * 256 + w * 64 + n * 16 + lrow) * 16);
        acc[n] = __builtin_amdgcn_mfma_f32_16x16x32_bf16(af, bf, acc[n], 0, 0, 0);
      }
    }
  }

  float s[4] = {0.0f, 0.0f, 0.0f, 0.0f};
#pragma unroll
  for (int n = 0; n < 4; ++n) {
    const int c = w * 64 + n * 16 + lrow;
    const float b1v = b1[c];
    const float w2v = W2[c];
#pragma unroll
    for (int i = 0; i < 4; ++i) {
      float f = acc[n][i] + b1v;
      f = fmaxf(f, 0.0f);
      s[i] = fmaf(f, w2v, s[i]);
    }
  }
#pragma unroll
  for (int off = 1; off < 16; off <<= 1) {
#pragma unroll
    for (int i = 0; i < 4; ++i) s[i] += __shfl_xor(s[i], off, 64);
  }
  if (lrow == 0) {
#pragma unroll
    for (int i = 0; i < 4; ++i) pr[w][lk * 4 + i] = s[i];
  }
  __syncthreads();
  if (t < 16) {
    out1[row0 + t] =
        (pr[0][t] + pr[1][t] + pr[2][t] + pr[3][t] + b2[0]) * (float)LROW;
  }
}

extern "C" void kernel_launch(void* const* d_in, const int* in_sizes, int n_in,
                              void* d_out, int out_size, void* d_ws, size_t ws_size,
                              hipStream_t stream) {
  const float* y     = (const float*)d_in[0];
  const float* pulse = (const float*)d_in[1];
  const float* W1    = (const float*)d_in[2];
  const float* b1    = (const float*)d_in[3];
  const float* W2    = (const float*)d_in[4];
  const float* b2    = (const float*)d_in[5];

  float* xout = (float*)d_out;
  float* out1 = xout + (size_t)LROW * LROW;
  unsigned short* W1p = (unsigned short*)d_ws;

  cast_w1<<<512, 256, 0, stream>>>(W1, W1p);
  ista_mfma<<<LROW, 256, 0, stream>>>(y, pulse, xout);
  mlp_mfma<<<LROW / 16, 256, 0, stream>>>(xout, W1p, b1, W2, b2, out1);
}